// Round 4
// baseline (121.236 us; speedup 1.0000x reference)
//
#include <hip/hip_runtime.h>

#define DIM 16
#define K_TOK 16   // tokens per 16-lane stream; fully unrolled

// Kernel 1: (a) out[b*DIM+d] = bias[d]; (b) stream the entire weight table
// through L3 (Infinity Cache is memory-side & shared, 64 MB table < 256 MB)
// so the gather kernel's random reads hit L3 instead of cold HBM.
// The harness's 268 MB ws-poison evicts L3 before every launch, so this
// re-warm is needed every call.
__global__ __launch_bounds__(256) void init_and_warm_kernel(
    float4* __restrict__ out4, const float* __restrict__ bias, int n4,
    const float4* __restrict__ w4, int w_n4,
    float* __restrict__ ws_sink) {
    int tid = blockIdx.x * blockDim.x + threadIdx.x;
    if (tid < n4) {
        int d = (tid & 3) * 4;   // DIM=16 -> 4 float4 per out row
        out4[tid] = make_float4(bias[d], bias[d + 1], bias[d + 2], bias[d + 3]);
    }
    // grid-stride streaming read of the weight table (warms L3)
    float acc = 0.0f;
    int stride = gridDim.x * blockDim.x;
    for (int i = tid; i < w_n4; i += stride) {
        float4 v = w4[i];
        acc += v.x + v.y + v.z + v.w;
    }
    // sink the value so the loads can't be dead-code-eliminated
    ws_sink[tid] = acc;
}

// Kernel 2: 16 lanes per stream (lane = dim), 16 consecutive tokens/stream.
// All index/rating/seg data loaded as dwordx4, all 16 weight-row gathers
// issued before any use. Sorted segment_ids -> register run-length
// accumulate; atomicAdd only at segment boundaries.
__global__ __launch_bounds__(256) void features_linear_kernel(
    const int*   __restrict__ ids,
    const float* __restrict__ ratings,
    const int*   __restrict__ segs,
    const float* __restrict__ weight,
    float*       __restrict__ out,
    int total) {
    int tid = blockIdx.x * blockDim.x + threadIdx.x;
    int d = tid & (DIM - 1);
    int stream_id = tid >> 4;
    int t0 = stream_id * K_TOK;
    if (t0 >= total) return;

    float acc = 0.0f;
    int prev = segs[t0];

    if (t0 + K_TOK <= total) {
        const int4*   idv = (const int4*)(ids + t0);
        const float4* rv  = (const float4*)(ratings + t0);
        const int4*   sv  = (const int4*)(segs + t0);

        int4   id0 = idv[0], id1 = idv[1], id2 = idv[2], id3 = idv[3];
        float4 r0  = rv[0],  r1  = rv[1],  r2  = rv[2],  r3  = rv[3];
        int4   s0  = sv[0],  s1  = sv[1],  s2  = sv[2],  s3  = sv[3];

        float w0  = weight[(size_t)id0.x * DIM + d];
        float w1  = weight[(size_t)id0.y * DIM + d];
        float w2  = weight[(size_t)id0.z * DIM + d];
        float w3  = weight[(size_t)id0.w * DIM + d];
        float w4  = weight[(size_t)id1.x * DIM + d];
        float w5  = weight[(size_t)id1.y * DIM + d];
        float w6  = weight[(size_t)id1.z * DIM + d];
        float w7  = weight[(size_t)id1.w * DIM + d];
        float w8  = weight[(size_t)id2.x * DIM + d];
        float w9  = weight[(size_t)id2.y * DIM + d];
        float w10 = weight[(size_t)id2.z * DIM + d];
        float w11 = weight[(size_t)id2.w * DIM + d];
        float w12 = weight[(size_t)id3.x * DIM + d];
        float w13 = weight[(size_t)id3.y * DIM + d];
        float w14 = weight[(size_t)id3.z * DIM + d];
        float w15 = weight[(size_t)id3.w * DIM + d];

        #define STEP(sv_, wv_, rv_)                                        \
            if ((sv_) != prev) {                                           \
                atomicAdd(&out[prev * DIM + d], acc);                      \
                acc = 0.0f; prev = (sv_);                                  \
            }                                                              \
            acc = fmaf((wv_), (rv_), acc);

        STEP(s0.x, w0,  r0.x)  STEP(s0.y, w1,  r0.y)
        STEP(s0.z, w2,  r0.z)  STEP(s0.w, w3,  r0.w)
        STEP(s1.x, w4,  r1.x)  STEP(s1.y, w5,  r1.y)
        STEP(s1.z, w6,  r1.z)  STEP(s1.w, w7,  r1.w)
        STEP(s2.x, w8,  r2.x)  STEP(s2.y, w9,  r2.y)
        STEP(s2.z, w10, r2.z)  STEP(s2.w, w11, r2.w)
        STEP(s3.x, w12, r3.x)  STEP(s3.y, w13, r3.y)
        STEP(s3.z, w14, r3.z)  STEP(s3.w, w15, r3.w)
        #undef STEP
    } else {
        for (int t = t0; t < total; ++t) {
            int seg = segs[t];
            if (seg != prev) {
                atomicAdd(&out[prev * DIM + d], acc);
                acc = 0.0f;
                prev = seg;
            }
            acc = fmaf(weight[(size_t)ids[t] * DIM + d], ratings[t], acc);
        }
    }
    atomicAdd(&out[prev * DIM + d], acc);
}

extern "C" void kernel_launch(void* const* d_in, const int* in_sizes, int n_in,
                              void* d_out, int out_size, void* d_ws, size_t ws_size,
                              hipStream_t stream) {
    const int*   ids     = (const int*)d_in[0];
    const float* ratings = (const float*)d_in[1];
    const int*   segs    = (const int*)d_in[2];
    // d_in[3] = batch_size scalar (unused; batch = out_size / DIM)
    const float* weight  = (const float*)d_in[4];
    const float* bias    = (const float*)d_in[5];
    float* out = (float*)d_out;

    int total   = in_sizes[0];
    int w_elems = in_sizes[4];          // VOCAB * DIM floats

    // 1) bias-init of out + L3 warm of the weight table (stream-ordered
    //    before the gather kernel)
    {
        int threads = 256;
        int blocks = 1024;              // 262144 threads, grid-stride warm
        int n4 = out_size / 4;
        int w_n4 = w_elems / 4;
        init_and_warm_kernel<<<blocks, threads, 0, stream>>>(
            (float4*)out, bias, n4, (const float4*)weight, w_n4,
            (float*)d_ws);
    }

    // 2) gather + segmented sum (weight rows now L3-resident)
    {
        int n_streams = (total + K_TOK - 1) / K_TOK;
        long long n_threads = (long long)n_streams * DIM;
        int threads = 256;
        int blocks = (int)((n_threads + threads - 1) / threads);
        features_linear_kernel<<<blocks, threads, 0, stream>>>(
            ids, ratings, segs, weight, out, total);
    }
}